// Round 6
// baseline (184.891 us; speedup 1.0000x reference)
//
#include <hip/hip_runtime.h>
#include <hip/hip_bf16.h>

typedef __bf16 bf16x8 __attribute__((ext_vector_type(8)));
typedef __bf16 bf16x4 __attribute__((ext_vector_type(4)));
typedef __bf16 bf16x2 __attribute__((ext_vector_type(2)));
typedef float  f32x4  __attribute__((ext_vector_type(4)));
typedef float  f32x16v __attribute__((ext_vector_type(16)));

#define MFMA16(A,B,Cc) __builtin_amdgcn_mfma_f32_16x16x32_bf16(A,B,Cc,0,0,0)
#define MFMA32(A,B,Cc) __builtin_amdgcn_mfma_f32_32x32x16_bf16(A,B,Cc,0,0,0)

__device__ inline unsigned pack2(float a, float b) {
  union { bf16x2 v; unsigned u; } t;
  t.v[0] = (__bf16)a; t.v[1] = (__bf16)b;
  return t.u;
}
__device__ inline bf16x8 frag4(unsigned w0, unsigned w1, unsigned w2, unsigned w3) {
  union { unsigned u[4]; bf16x8 v; } t;
  t.u[0] = w0; t.u[1] = w1; t.u[2] = w2; t.u[3] = w3;
  return t.v;
}

// ---------------- f32 -> bf16 pre-convert (x + 4 weight matrices) ----------------
__global__ __launch_bounds__(256) void conv_kernel(
    const float* __restrict__ x,
    const float* __restrict__ Wq, const float* __restrict__ Wk,
    const float* __restrict__ Wv, const float* __restrict__ Wp,
    __bf16* __restrict__ xb, __bf16* __restrict__ Wb)
{
  const int z = blockIdx.y;
  const float* src;
  __bf16* dst;
  int n4;
  if (z == 0) { src = x;  dst = xb; n4 = 1048576; }
  else {
    src = (z == 1) ? Wq : (z == 2) ? Wk : (z == 3) ? Wv : Wp;
    dst = Wb + (size_t)(z - 1) * 1048576;
    n4  = 262144;
  }
  const f32x4* s4 = (const f32x4*)src;
  for (int i = blockIdx.x * 256 + threadIdx.x; i < n4; i += gridDim.x * 256) {
    const f32x4 v = s4[i];
    bf16x4 o;
#pragma unroll
    for (int j = 0; j < 4; ++j) o[j] = (__bf16)v[j];
    *(bf16x4*)(dst + (size_t)i * 4) = o;
  }
}

// ---------------- shared 128x128x(K=1024) bf16 MFMA core ----------------
__device__ inline void gemm_core(const __bf16* __restrict__ A,
                                 const __bf16* __restrict__ W,
                                 int m0, int n0,
                                 __bf16* As, __bf16* Bs,
                                 f32x4 (&acc)[4][4])
{
  const int tid = threadIdx.x, lane = tid & 63;
  const int wid = tid >> 6, wr = wid >> 1, wc = wid & 1;
  const int g = lane >> 4, cl = lane & 15;
  const int sr = tid >> 2, sk = (tid & 3) * 8;

  for (int k0 = 0; k0 < 1024; k0 += 32) {
    bf16x8 a0 = *(const bf16x8*)(A + (size_t)(m0 + sr)      * 1024 + k0 + sk);
    bf16x8 a1 = *(const bf16x8*)(A + (size_t)(m0 + sr + 64) * 1024 + k0 + sk);
    bf16x8 b0 = *(const bf16x8*)(W + (size_t)(n0 + sr)      * 1024 + k0 + sk);
    bf16x8 b1 = *(const bf16x8*)(W + (size_t)(n0 + sr + 64) * 1024 + k0 + sk);
    __syncthreads();
    *(bf16x8*)(As + sr * 32 + sk)        = a0;
    *(bf16x8*)(As + (sr + 64) * 32 + sk) = a1;
    *(bf16x8*)(Bs + sr * 32 + sk)        = b0;
    *(bf16x8*)(Bs + (sr + 64) * 32 + sk) = b1;
    __syncthreads();
    bf16x8 af[4], bfr[4];
#pragma unroll
    for (int m = 0; m < 4; ++m)
      af[m] = *(const bf16x8*)(As + (wr * 64 + m * 16 + cl) * 32 + g * 8);
#pragma unroll
    for (int n = 0; n < 4; ++n)
      bfr[n] = *(const bf16x8*)(Bs + (wc * 64 + n * 16 + cl) * 32 + g * 8);
#pragma unroll
    for (int m = 0; m < 4; ++m)
#pragma unroll
      for (int n = 0; n < 4; ++n)
        acc[m][n] = MFMA16(af[m], bfr[n], acc[m][n]);
  }
}

// ---------------- fused QKV GEMM (bf16 in, scattered bf16 out) ----------------
__global__ __launch_bounds__(256) void gemm_qkv128(
    const __bf16* __restrict__ xb, const __bf16* __restrict__ Wb,
    const float* __restrict__ bq, const float* __restrict__ bk,
    const float* __restrict__ bv,
    __bf16* __restrict__ Qw, __bf16* __restrict__ Kw, __bf16* __restrict__ Vw)
{
  __shared__ __align__(16) __bf16 As[128 * 32];
  __shared__ __align__(16) __bf16 Bs[128 * 32];

  const int orig = blockIdx.x;
  const int wg   = (orig & 7) * 96 + (orig >> 3);   // bijective: 768 = 8*96
  const int z    = wg >> 8;
  const int rem  = wg & 255;
  const int m0   = (rem >> 3) * 128;
  const int n0   = (rem & 7) * 128;

  const __bf16* W  = Wb + (size_t)z * 1048576;
  const float*  bi = (z == 0) ? bq : (z == 1) ? bk : bv;
  __bf16*       out = (z == 0) ? Qw : (z == 1) ? Kw : Vw;

  f32x4 acc[4][4] = {};
  gemm_core(xb, W, m0, n0, As, Bs, acc);

  const int lane = threadIdx.x & 63, wid = threadIdx.x >> 6;
  const int wr = wid >> 1, wc = wid & 1;
  const int g = lane >> 4, cl = lane & 15;

  float bvv[4];
#pragma unroll
  for (int n = 0; n < 4; ++n) bvv[n] = bi[n0 + wc * 64 + n * 16 + cl];

#pragma unroll
  for (int m = 0; m < 4; ++m)
#pragma unroll
    for (int n = 0; n < 4; ++n) {
      const int col = n0 + wc * 64 + n * 16 + cl;
      const int h = col >> 6, d = col & 63;
      if (z == 2) {                               // V^T scatter [BH][D][T]
        const int row0 = m0 + wr * 64 + m * 16 + g * 4;
        const int b2 = row0 >> 11, t0 = row0 & 2047;
        bf16x4 v4;
#pragma unroll
        for (int j = 0; j < 4; ++j) v4[j] = (__bf16)(acc[m][n][j] + bvv[n]);
        *(bf16x4*)(out + (size_t)(b2 * 16 + h) * 131072 + (size_t)d * 2048 + t0) = v4;
      } else {                                    // Q/K scatter [BH][T][D]
#pragma unroll
        for (int j = 0; j < 4; ++j) {
          const int row = m0 + wr * 64 + m * 16 + g * 4 + j;
          const int b2 = row >> 11, t = row & 2047;
          out[(size_t)(b2 * 16 + h) * 131072 + (size_t)t * 64 + d] =
              (__bf16)(acc[m][n][j] + bvv[n]);
        }
      }
    }
}

// ---------------- projection GEMM (bf16 in, f32 out) ----------------
__global__ __launch_bounds__(256) void gemm_proj128(
    const __bf16* __restrict__ A, const __bf16* __restrict__ W,
    const float* __restrict__ bi, float* __restrict__ outp)
{
  __shared__ __align__(16) __bf16 As[128 * 32];
  __shared__ __align__(16) __bf16 Bs[128 * 32];

  const int orig = blockIdx.x;
  const int wg   = (orig & 7) * 32 + (orig >> 3);   // bijective: 256 = 8*32
  const int m0   = (wg >> 3) * 128;
  const int n0   = (wg & 7) * 128;

  f32x4 acc[4][4] = {};
  gemm_core(A, W, m0, n0, As, Bs, acc);

  const int lane = threadIdx.x & 63, wid = threadIdx.x >> 6;
  const int wr = wid >> 1, wc = wid & 1;
  const int g = lane >> 4, cl = lane & 15;

  float bvv[4];
#pragma unroll
  for (int n = 0; n < 4; ++n) bvv[n] = bi[n0 + wc * 64 + n * 16 + cl];
#pragma unroll
  for (int m = 0; m < 4; ++m)
#pragma unroll
    for (int n = 0; n < 4; ++n) {
      const int col = n0 + wc * 64 + n * 16 + cl;
#pragma unroll
      for (int j = 0; j < 4; ++j) {
        const int row = m0 + wr * 64 + m * 16 + g * 4 + j;
        outp[(size_t)row * 1024 + col] = acc[m][n][j] + bvv[n];
      }
    }
}

// ---------------- causal flash attention, swapped-QK 32x32, KV-split x4 ----------------
// Q,K: [BH][T][64]; Vt: [BH][64][T]; out: [B*T][1024], all bf16.
// Block = 256 threads = 4 waves; all own the same 32-row q-strip, disjoint
// quarters of its kv-range; 4-way merge via LDS online-softmax combine.
__global__ __launch_bounds__(256, 6) void attn_kernel(
    const __bf16* __restrict__ Q, const __bf16* __restrict__ K,
    const __bf16* __restrict__ Vt, __bf16* __restrict__ Oc)
{
  const int bh    = blockIdx.x;
  const int strip = 63 - (int)blockIdx.y;       // long strips dispatch first
  const int wid   = threadIdx.x >> 6;
  const int lane  = threadIdx.x & 63;
  const int l31 = lane & 31, hi = lane >> 5;
  const int qs = strip * 32;

  const __bf16* Qb = Q  + (size_t)bh * 131072;
  const __bf16* Kb = K  + (size_t)bh * 131072;
  const __bf16* Vb = Vt + (size_t)bh * 131072;

  const int ntiles = strip + 1;
  const int tBeg = (wid * ntiles) >> 2;
  const int tEnd = ((wid + 1) * ntiles) >> 2;

  bf16x8 qf[4];
#pragma unroll
  for (int c = 0; c < 4; ++c)
    qf[c] = *(const bf16x8*)(Qb + (qs + l31) * 64 + c * 16 + hi * 8);

  f32x16v o0 = {}, o1 = {};
  float M = -1e30f, L = 0.f;
  const float SC = 0.18033688f;                 // 0.125 * log2(e)
  const float DT = 16.6f;                       // defer-max: P bounded by 2^3
  float MS = M * SC;

  const __bf16* vrow0 = Vb + (size_t)l31 * 2048;
  const __bf16* vrow1 = Vb + (size_t)(32 + l31) * 2048;

  for (int t = tBeg; t < tEnd; ++t) {
    const int kv0 = t * 32;
    f32x16v s = {};
#pragma unroll
    for (int c = 0; c < 4; ++c) {
      bf16x8 kf = *(const bf16x8*)(Kb + (kv0 + l31) * 64 + c * 16 + hi * 8);
      s = MFMA32(kf, qf[c], s);
    }
    float sv[16];
#pragma unroll
    for (int r = 0; r < 16; ++r) sv[r] = s[r];
    if (t == ntiles - 1) {                      // diagonal tile: mask k > q
#pragma unroll
      for (int r = 0; r < 16; ++r) {
        const int kl = (r & 3) + 8 * (r >> 2) + 4 * hi;
        if (kl > l31) sv[r] = -1e30f;
      }
    }
    float mt = sv[0];
#pragma unroll
    for (int r = 1; r < 16; ++r) mt = fmaxf(mt, sv[r]);
    mt = fmaxf(mt, __shfl_xor(mt, 32, 64));
    if (!__all(mt <= M + DT)) {                 // deferred rescale
      const float Mn = fmaxf(M, mt);
      const float rs = exp2f((M - Mn) * SC);
      o0 *= rs; o1 *= rs; L *= rs; M = Mn; MS = M * SC;
    }
    float p[16];
    float lt = 0.f;
#pragma unroll
    for (int r = 0; r < 16; ++r) {
      p[r] = exp2f(__builtin_fmaf(sv[r], SC, -MS));
      lt += p[r];
    }
    lt += __shfl_xor(lt, 32, 64);
    L += lt;

    const unsigned c0 = pack2(p[0],  p[1]),  c1 = pack2(p[2],  p[3]);
    const unsigned c2 = pack2(p[4],  p[5]),  c3 = pack2(p[6],  p[7]);
    const unsigned c4 = pack2(p[8],  p[9]),  c5 = pack2(p[10], p[11]);
    const unsigned c6 = pack2(p[12], p[13]), c7 = pack2(p[14], p[15]);
    const unsigned x0 = __shfl_xor(c0, 32, 64), x1 = __shfl_xor(c1, 32, 64);
    const unsigned x2 = __shfl_xor(c2, 32, 64), x3 = __shfl_xor(c3, 32, 64);
    const unsigned x4 = __shfl_xor(c4, 32, 64), x5 = __shfl_xor(c5, 32, 64);
    const unsigned x6 = __shfl_xor(c6, 32, 64), x7 = __shfl_xor(c7, 32, 64);
    const bf16x8 pf0 = frag4(hi ? x2 : c0, hi ? x3 : c1, hi ? c2 : x0, hi ? c3 : x1);
    const bf16x8 pf1 = frag4(hi ? x6 : c4, hi ? x7 : c5, hi ? c6 : x4, hi ? c7 : x5);

    bf16x8 va;
    va = *(const bf16x8*)(vrow0 + kv0 + hi * 8);       o0 = MFMA32(va, pf0, o0);
    va = *(const bf16x8*)(vrow0 + kv0 + 16 + hi * 8);  o0 = MFMA32(va, pf1, o0);
    va = *(const bf16x8*)(vrow1 + kv0 + hi * 8);       o1 = MFMA32(va, pf0, o1);
    va = *(const bf16x8*)(vrow1 + kv0 + 16 + hi * 8);  o1 = MFMA32(va, pf1, o1);
  }

  // ---- 4-way merge through LDS (waves 1..3 publish; wave 0 combines) ----
  __shared__ float Sm[3][64][35];               // stride 35: 2 lanes/bank, free
  if (wid != 0) {
    float* dst = &Sm[wid - 1][lane][0];
#pragma unroll
    for (int q4 = 0; q4 < 4; ++q4) {
      f32x4 a = { o0[q4*4+0], o0[q4*4+1], o0[q4*4+2], o0[q4*4+3] };
      f32x4 b = { o1[q4*4+0], o1[q4*4+1], o1[q4*4+2], o1[q4*4+3] };
      *(f32x4*)(dst + q4 * 4)      = a;
      *(f32x4*)(dst + 16 + q4 * 4) = b;
    }
    dst[32] = M;
    dst[33] = L;
  }
  __syncthreads();
  if (wid == 0) {
    float Mw[3], Lw[3];
#pragma unroll
    for (int w = 0; w < 3; ++w) {
      Mw[w] = Sm[w][lane][32];
      Lw[w] = Sm[w][lane][33];
    }
    float Ms = fmaxf(fmaxf(M, Mw[0]), fmaxf(Mw[1], Mw[2]));
    const float r0 = exp2f((M - Ms) * SC);
    float rw[3];
    float Lt = L * r0;
#pragma unroll
    for (int w = 0; w < 3; ++w) {
      rw[w] = exp2f((Mw[w] - Ms) * SC);
      Lt += Lw[w] * rw[w];
    }
    const float inv = 1.0f / Lt;

    const int b = bh >> 4, h = bh & 15;
    const int tq = qs + l31;
    __bf16* orow = Oc + (size_t)(b * 2048 + tq) * 1024 + h * 64;
#pragma unroll
    for (int q4 = 0; q4 < 4; ++q4) {
      bf16x4 v0, v1;
#pragma unroll
      for (int j = 0; j < 4; ++j) {
        const int r = q4 * 4 + j;
        float a = o0[r] * r0;
        float bb2 = o1[r] * r0;
#pragma unroll
        for (int w = 0; w < 3; ++w) {
          a   += Sm[w][lane][r]      * rw[w];
          bb2 += Sm[w][lane][16 + r] * rw[w];
        }
        v0[j] = (__bf16)(a * inv);
        v1[j] = (__bf16)(bb2 * inv);
      }
      const int d0 = 8 * q4 + 4 * hi;
      *(bf16x4*)(orow + d0)      = v0;
      *(bf16x4*)(orow + 32 + d0) = v1;
    }
  }
}

extern "C" void kernel_launch(void* const* d_in, const int* in_sizes, int n_in,
                              void* d_out, int out_size, void* d_ws, size_t ws_size,
                              hipStream_t stream) {
  const float* x  = (const float*)d_in[0];
  const float* Wq = (const float*)d_in[1];
  const float* bq = (const float*)d_in[2];
  const float* Wk = (const float*)d_in[3];
  const float* bk = (const float*)d_in[4];
  const float* Wv = (const float*)d_in[5];
  const float* bv = (const float*)d_in[6];
  const float* Wp = (const float*)d_in[7];
  const float* bp = (const float*)d_in[8];

  __bf16* Qw  = (__bf16*)d_ws;                 // [32][2048][64]  8 MB
  __bf16* Kw  = Qw + (size_t)4194304;          // [32][2048][64]  8 MB
  __bf16* Vw  = Kw + (size_t)4194304;          // [32][64][2048]  8 MB (V^T)
  __bf16* xbA = Vw + (size_t)4194304;          // 8 MB: xb, then reused as Aw
  __bf16* Wb  = xbA + (size_t)4194304;         // [4][1024][1024] 8 MB bf16 weights

  conv_kernel<<<dim3(512, 5), 256, 0, stream>>>(x, Wq, Wk, Wv, Wp, xbA, Wb);
  gemm_qkv128<<<768, 256, 0, stream>>>(xbA, Wb, bq, bk, bv, Qw, Kw, Vw);
  attn_kernel<<<dim3(32, 64), 256, 0, stream>>>(Qw, Kw, Vw, xbA /*Aw*/);
  gemm_proj128<<<256, 256, 0, stream>>>(xbA /*Aw*/, Wb + (size_t)3 * 1048576,
                                        bp, (float*)d_out);
}

// Round 7
// 149.574 us; speedup vs baseline: 1.2361x; 1.2361x over previous
//
#include <hip/hip_runtime.h>
#include <hip/hip_bf16.h>

typedef __bf16 bf16x8 __attribute__((ext_vector_type(8)));
typedef __bf16 bf16x4 __attribute__((ext_vector_type(4)));
typedef __bf16 bf16x2 __attribute__((ext_vector_type(2)));
typedef float  f32x4  __attribute__((ext_vector_type(4)));
typedef float  f32x16v __attribute__((ext_vector_type(16)));

#define MFMA16(A,B,Cc) __builtin_amdgcn_mfma_f32_16x16x32_bf16(A,B,Cc,0,0,0)
#define MFMA32(A,B,Cc) __builtin_amdgcn_mfma_f32_32x32x16_bf16(A,B,Cc,0,0,0)

__device__ inline unsigned pack2(float a, float b) {
  union { bf16x2 v; unsigned u; } t;
  t.v[0] = (__bf16)a; t.v[1] = (__bf16)b;
  return t.u;
}
__device__ inline bf16x8 frag4(unsigned w0, unsigned w1, unsigned w2, unsigned w3) {
  union { unsigned u[4]; bf16x8 v; } t;
  t.u[0] = w0; t.u[1] = w1; t.u[2] = w2; t.u[3] = w3;
  return t.v;
}
__device__ inline float hmax16(const f32x16v& v) {
  float a = fmaxf(v[0], v[1]),  b = fmaxf(v[2], v[3]);
  float c = fmaxf(v[4], v[5]),  d = fmaxf(v[6], v[7]);
  float e = fmaxf(v[8], v[9]),  f = fmaxf(v[10], v[11]);
  float g = fmaxf(v[12], v[13]), h = fmaxf(v[14], v[15]);
  return fmaxf(fmaxf(fmaxf(a, b), fmaxf(c, d)),
               fmaxf(fmaxf(e, f), fmaxf(g, h)));
}
__device__ inline float hsum16(const f32x16v& v) {
  float a = v[0] + v[1],  b = v[2] + v[3];
  float c = v[4] + v[5],  d = v[6] + v[7];
  float e = v[8] + v[9],  f = v[10] + v[11];
  float g = v[12] + v[13], h = v[14] + v[15];
  return ((a + b) + (c + d)) + ((e + f) + (g + h));
}

// ---------------- f32 -> bf16 pre-convert (x + 4 weight matrices) ----------------
__global__ __launch_bounds__(256) void conv_kernel(
    const float* __restrict__ x,
    const float* __restrict__ Wq, const float* __restrict__ Wk,
    const float* __restrict__ Wv, const float* __restrict__ Wp,
    __bf16* __restrict__ xb, __bf16* __restrict__ Wb)
{
  const int z = blockIdx.y;
  const float* src;
  __bf16* dst;
  int n4;
  if (z == 0) { src = x;  dst = xb; n4 = 1048576; }
  else {
    src = (z == 1) ? Wq : (z == 2) ? Wk : (z == 3) ? Wv : Wp;
    dst = Wb + (size_t)(z - 1) * 1048576;
    n4  = 262144;
  }
  const f32x4* s4 = (const f32x4*)src;
  for (int i = blockIdx.x * 256 + threadIdx.x; i < n4; i += gridDim.x * 256) {
    const f32x4 v = s4[i];
    bf16x4 o;
#pragma unroll
    for (int j = 0; j < 4; ++j) o[j] = (__bf16)v[j];
    *(bf16x4*)(dst + (size_t)i * 4) = o;
  }
}

// ---------------- shared 128x128x(K=1024) bf16 MFMA core ----------------
__device__ inline void gemm_core(const __bf16* __restrict__ A,
                                 const __bf16* __restrict__ W,
                                 int m0, int n0,
                                 __bf16* As, __bf16* Bs,
                                 f32x4 (&acc)[4][4])
{
  const int tid = threadIdx.x, lane = tid & 63;
  const int wid = tid >> 6, wr = wid >> 1, wc = wid & 1;
  const int g = lane >> 4, cl = lane & 15;
  const int sr = tid >> 2, sk = (tid & 3) * 8;

  for (int k0 = 0; k0 < 1024; k0 += 32) {
    bf16x8 a0 = *(const bf16x8*)(A + (size_t)(m0 + sr)      * 1024 + k0 + sk);
    bf16x8 a1 = *(const bf16x8*)(A + (size_t)(m0 + sr + 64) * 1024 + k0 + sk);
    bf16x8 b0 = *(const bf16x8*)(W + (size_t)(n0 + sr)      * 1024 + k0 + sk);
    bf16x8 b1 = *(const bf16x8*)(W + (size_t)(n0 + sr + 64) * 1024 + k0 + sk);
    __syncthreads();
    *(bf16x8*)(As + sr * 32 + sk)        = a0;
    *(bf16x8*)(As + (sr + 64) * 32 + sk) = a1;
    *(bf16x8*)(Bs + sr * 32 + sk)        = b0;
    *(bf16x8*)(Bs + (sr + 64) * 32 + sk) = b1;
    __syncthreads();
    bf16x8 af[4], bfr[4];
#pragma unroll
    for (int m = 0; m < 4; ++m)
      af[m] = *(const bf16x8*)(As + (wr * 64 + m * 16 + cl) * 32 + g * 8);
#pragma unroll
    for (int n = 0; n < 4; ++n)
      bfr[n] = *(const bf16x8*)(Bs + (wc * 64 + n * 16 + cl) * 32 + g * 8);
#pragma unroll
    for (int m = 0; m < 4; ++m)
#pragma unroll
      for (int n = 0; n < 4; ++n)
        acc[m][n] = MFMA16(af[m], bfr[n], acc[m][n]);
  }
}

// ---------------- fused QKV GEMM (bf16 in, scattered bf16 out) ----------------
__global__ __launch_bounds__(256) void gemm_qkv128(
    const __bf16* __restrict__ xb, const __bf16* __restrict__ Wb,
    const float* __restrict__ bq, const float* __restrict__ bk,
    const float* __restrict__ bv,
    __bf16* __restrict__ Qw, __bf16* __restrict__ Kw, __bf16* __restrict__ Vw)
{
  __shared__ __align__(16) __bf16 As[128 * 32];
  __shared__ __align__(16) __bf16 Bs[128 * 32];

  const int orig = blockIdx.x;
  const int wg   = (orig & 7) * 96 + (orig >> 3);   // bijective: 768 = 8*96
  const int z    = wg >> 8;
  const int rem  = wg & 255;
  const int m0   = (rem >> 3) * 128;
  const int n0   = (rem & 7) * 128;

  const __bf16* W  = Wb + (size_t)z * 1048576;
  const float*  bi = (z == 0) ? bq : (z == 1) ? bk : bv;
  __bf16*       out = (z == 0) ? Qw : (z == 1) ? Kw : Vw;

  f32x4 acc[4][4] = {};
  gemm_core(xb, W, m0, n0, As, Bs, acc);

  const int lane = threadIdx.x & 63, wid = threadIdx.x >> 6;
  const int wr = wid >> 1, wc = wid & 1;
  const int g = lane >> 4, cl = lane & 15;

  float bvv[4];
#pragma unroll
  for (int n = 0; n < 4; ++n) bvv[n] = bi[n0 + wc * 64 + n * 16 + cl];

#pragma unroll
  for (int m = 0; m < 4; ++m)
#pragma unroll
    for (int n = 0; n < 4; ++n) {
      const int col = n0 + wc * 64 + n * 16 + cl;
      const int h = col >> 6, d = col & 63;
      if (z == 2) {                               // V^T scatter [BH][D][T]
        const int row0 = m0 + wr * 64 + m * 16 + g * 4;
        const int b2 = row0 >> 11, t0 = row0 & 2047;
        bf16x4 v4;
#pragma unroll
        for (int j = 0; j < 4; ++j) v4[j] = (__bf16)(acc[m][n][j] + bvv[n]);
        *(bf16x4*)(out + (size_t)(b2 * 16 + h) * 131072 + (size_t)d * 2048 + t0) = v4;
      } else {                                    // Q/K scatter [BH][T][D]
#pragma unroll
        for (int j = 0; j < 4; ++j) {
          const int row = m0 + wr * 64 + m * 16 + g * 4 + j;
          const int b2 = row >> 11, t = row & 2047;
          out[(size_t)(b2 * 16 + h) * 131072 + (size_t)t * 64 + d] =
              (__bf16)(acc[m][n][j] + bvv[n]);
        }
      }
    }
}

// ---------------- projection GEMM (bf16 in, f32 out) ----------------
__global__ __launch_bounds__(256) void gemm_proj128(
    const __bf16* __restrict__ A, const __bf16* __restrict__ W,
    const float* __restrict__ bi, float* __restrict__ outp)
{
  __shared__ __align__(16) __bf16 As[128 * 32];
  __shared__ __align__(16) __bf16 Bs[128 * 32];

  const int orig = blockIdx.x;
  const int wg   = (orig & 7) * 32 + (orig >> 3);   // bijective: 256 = 8*32
  const int m0   = (wg >> 3) * 128;
  const int n0   = (wg & 7) * 128;

  f32x4 acc[4][4] = {};
  gemm_core(A, W, m0, n0, As, Bs, acc);

  const int lane = threadIdx.x & 63, wid = threadIdx.x >> 6;
  const int wr = wid >> 1, wc = wid & 1;
  const int g = lane >> 4, cl = lane & 15;

  float bvv[4];
#pragma unroll
  for (int n = 0; n < 4; ++n) bvv[n] = bi[n0 + wc * 64 + n * 16 + cl];
#pragma unroll
  for (int m = 0; m < 4; ++m)
#pragma unroll
    for (int n = 0; n < 4; ++n) {
      const int col = n0 + wc * 64 + n * 16 + cl;
#pragma unroll
      for (int j = 0; j < 4; ++j) {
        const int row = m0 + wr * 64 + m * 16 + g * 4 + j;
        outp[(size_t)row * 1024 + col] = acc[m][n][j] + bvv[n];
      }
    }
}

// ---------------- causal flash attention: swapped-QK 32x32, KV-split x2, KVBLK=64 ----
// Round-5 structure (128-thr blocks, full co-residency, 12 MB fetch) with
// two-tile pipelining: joint softmax per 64 kv cols, interleaved MFMA chains.
__global__ __launch_bounds__(128, 4) void attn_kernel(
    const __bf16* __restrict__ Q, const __bf16* __restrict__ K,
    const __bf16* __restrict__ Vt, __bf16* __restrict__ Oc)
{
  const int bh    = blockIdx.x;
  const int strip = 63 - (int)blockIdx.y;       // long strips dispatch first
  const int wid   = threadIdx.x >> 6;
  const int lane  = threadIdx.x & 63;
  const int l31 = lane & 31, hi = lane >> 5;
  const int qs = strip * 32;

  const __bf16* Qb = Q  + (size_t)bh * 131072;
  const __bf16* Kb = K  + (size_t)bh * 131072;
  const __bf16* Vb = Vt + (size_t)bh * 131072;

  const int ntiles = strip + 1;
  const int nA   = (ntiles + 1) >> 1;
  const int tBeg = wid ? nA : 0;
  const int tEnd = wid ? ntiles : nA;

  bf16x8 qf[4];
#pragma unroll
  for (int c = 0; c < 4; ++c)
    qf[c] = *(const bf16x8*)(Qb + (qs + l31) * 64 + c * 16 + hi * 8);

  f32x16v o0 = {}, o1 = {};
  float M = -1e30f, L = 0.f;
  const float SC = 0.18033688f;                 // 0.125 * log2(e)
  const float DT = 16.6f;                       // defer-max: P bounded by 2^3
  float MS = M * SC;

  const __bf16* vrow0 = Vb + (size_t)l31 * 2048;
  const __bf16* vrow1 = Vb + (size_t)(32 + l31) * 2048;

  int t = tBeg;
  // ---- pairwise main loop: 2 kv-tiles (64 cols) per iteration ----
  for (; t + 2 <= tEnd; t += 2) {
    const int kv0 = t * 32, kv1 = kv0 + 32;
    f32x16v sa = {}, sb = {};
#pragma unroll
    for (int c = 0; c < 4; ++c) {
      bf16x8 kfa = *(const bf16x8*)(Kb + (kv0 + l31) * 64 + c * 16 + hi * 8);
      bf16x8 kfb = *(const bf16x8*)(Kb + (kv1 + l31) * 64 + c * 16 + hi * 8);
      sa = MFMA32(kfa, qf[c], sa);
      sb = MFMA32(kfb, qf[c], sb);
    }
    if (t + 1 == ntiles - 1) {                  // diagonal in second tile
#pragma unroll
      for (int r = 0; r < 16; ++r) {
        const int kl = (r & 3) + 8 * (r >> 2) + 4 * hi;
        if (kl > l31) sb[r] = -1e30f;
      }
    }
    float mt = fmaxf(hmax16(sa), hmax16(sb));
    mt = fmaxf(mt, __shfl_xor(mt, 32, 64));
    if (!__all(mt <= M + DT)) {
      const float Mn = fmaxf(M, mt);
      const float rs = exp2f((M - Mn) * SC);
      o0 *= rs; o1 *= rs; L *= rs; M = Mn; MS = M * SC;
    }
#pragma unroll
    for (int r = 0; r < 16; ++r) {
      sa[r] = exp2f(__builtin_fmaf(sa[r], SC, -MS));
      sb[r] = exp2f(__builtin_fmaf(sb[r], SC, -MS));
    }
    float lt = hsum16(sa) + hsum16(sb);
    lt += __shfl_xor(lt, 32, 64);
    L += lt;

    const unsigned a0 = pack2(sa[0],  sa[1]),  a1 = pack2(sa[2],  sa[3]);
    const unsigned a2 = pack2(sa[4],  sa[5]),  a3 = pack2(sa[6],  sa[7]);
    const unsigned a4 = pack2(sa[8],  sa[9]),  a5 = pack2(sa[10], sa[11]);
    const unsigned a6 = pack2(sa[12], sa[13]), a7 = pack2(sa[14], sa[15]);
    const unsigned b0 = pack2(sb[0],  sb[1]),  b1 = pack2(sb[2],  sb[3]);
    const unsigned b2 = pack2(sb[4],  sb[5]),  b3 = pack2(sb[6],  sb[7]);
    const unsigned b4 = pack2(sb[8],  sb[9]),  b5 = pack2(sb[10], sb[11]);
    const unsigned b6 = pack2(sb[12], sb[13]), b7 = pack2(sb[14], sb[15]);
    const unsigned xa0 = __shfl_xor(a0, 32, 64), xa1 = __shfl_xor(a1, 32, 64);
    const unsigned xa2 = __shfl_xor(a2, 32, 64), xa3 = __shfl_xor(a3, 32, 64);
    const unsigned xa4 = __shfl_xor(a4, 32, 64), xa5 = __shfl_xor(a5, 32, 64);
    const unsigned xa6 = __shfl_xor(a6, 32, 64), xa7 = __shfl_xor(a7, 32, 64);
    const unsigned xb0 = __shfl_xor(b0, 32, 64), xb1 = __shfl_xor(b1, 32, 64);
    const unsigned xb2 = __shfl_xor(b2, 32, 64), xb3 = __shfl_xor(b3, 32, 64);
    const unsigned xb4 = __shfl_xor(b4, 32, 64), xb5 = __shfl_xor(b5, 32, 64);
    const unsigned xb6 = __shfl_xor(b6, 32, 64), xb7 = __shfl_xor(b7, 32, 64);
    const bf16x8 pf0a = frag4(hi ? xa2 : a0, hi ? xa3 : a1, hi ? a2 : xa0, hi ? a3 : xa1);
    const bf16x8 pf1a = frag4(hi ? xa6 : a4, hi ? xa7 : a5, hi ? a6 : xa4, hi ? a7 : xa5);
    const bf16x8 pf0b = frag4(hi ? xb2 : b0, hi ? xb3 : b1, hi ? b2 : xb0, hi ? b3 : xb1);
    const bf16x8 pf1b = frag4(hi ? xb6 : b4, hi ? xb7 : b5, hi ? b6 : xb4, hi ? b7 : xb5);

    bf16x8 va;
    va = *(const bf16x8*)(vrow0 + kv0 + hi * 8);       o0 = MFMA32(va, pf0a, o0);
    va = *(const bf16x8*)(vrow1 + kv0 + hi * 8);       o1 = MFMA32(va, pf0a, o1);
    va = *(const bf16x8*)(vrow0 + kv0 + 16 + hi * 8);  o0 = MFMA32(va, pf1a, o0);
    va = *(const bf16x8*)(vrow1 + kv0 + 16 + hi * 8);  o1 = MFMA32(va, pf1a, o1);
    va = *(const bf16x8*)(vrow0 + kv1 + hi * 8);       o0 = MFMA32(va, pf0b, o0);
    va = *(const bf16x8*)(vrow1 + kv1 + hi * 8);       o1 = MFMA32(va, pf0b, o1);
    va = *(const bf16x8*)(vrow0 + kv1 + 16 + hi * 8);  o0 = MFMA32(va, pf1b, o0);
    va = *(const bf16x8*)(vrow1 + kv1 + 16 + hi * 8);  o1 = MFMA32(va, pf1b, o1);
  }
  // ---- leftover single tile ----
  if (t < tEnd) {
    const int kv0 = t * 32;
    f32x16v sa = {};
#pragma unroll
    for (int c = 0; c < 4; ++c) {
      bf16x8 kf = *(const bf16x8*)(Kb + (kv0 + l31) * 64 + c * 16 + hi * 8);
      sa = MFMA32(kf, qf[c], sa);
    }
    if (t == ntiles - 1) {
#pragma unroll
      for (int r = 0; r < 16; ++r) {
        const int kl = (r & 3) + 8 * (r >> 2) + 4 * hi;
        if (kl > l31) sa[r] = -1e30f;
      }
    }
    float mt = hmax16(sa);
    mt = fmaxf(mt, __shfl_xor(mt, 32, 64));
    if (!__all(mt <= M + DT)) {
      const float Mn = fmaxf(M, mt);
      const float rs = exp2f((M - Mn) * SC);
      o0 *= rs; o1 *= rs; L *= rs; M = Mn; MS = M * SC;
    }
#pragma unroll
    for (int r = 0; r < 16; ++r)
      sa[r] = exp2f(__builtin_fmaf(sa[r], SC, -MS));
    float lt = hsum16(sa);
    lt += __shfl_xor(lt, 32, 64);
    L += lt;

    const unsigned a0 = pack2(sa[0],  sa[1]),  a1 = pack2(sa[2],  sa[3]);
    const unsigned a2 = pack2(sa[4],  sa[5]),  a3 = pack2(sa[6],  sa[7]);
    const unsigned a4 = pack2(sa[8],  sa[9]),  a5 = pack2(sa[10], sa[11]);
    const unsigned a6 = pack2(sa[12], sa[13]), a7 = pack2(sa[14], sa[15]);
    const unsigned xa0 = __shfl_xor(a0, 32, 64), xa1 = __shfl_xor(a1, 32, 64);
    const unsigned xa2 = __shfl_xor(a2, 32, 64), xa3 = __shfl_xor(a3, 32, 64);
    const unsigned xa4 = __shfl_xor(a4, 32, 64), xa5 = __shfl_xor(a5, 32, 64);
    const unsigned xa6 = __shfl_xor(a6, 32, 64), xa7 = __shfl_xor(a7, 32, 64);
    const bf16x8 pf0a = frag4(hi ? xa2 : a0, hi ? xa3 : a1, hi ? a2 : xa0, hi ? a3 : xa1);
    const bf16x8 pf1a = frag4(hi ? xa6 : a4, hi ? xa7 : a5, hi ? a6 : xa4, hi ? a7 : xa5);

    bf16x8 va;
    va = *(const bf16x8*)(vrow0 + kv0 + hi * 8);       o0 = MFMA32(va, pf0a, o0);
    va = *(const bf16x8*)(vrow1 + kv0 + hi * 8);       o1 = MFMA32(va, pf0a, o1);
    va = *(const bf16x8*)(vrow0 + kv0 + 16 + hi * 8);  o0 = MFMA32(va, pf1a, o0);
    va = *(const bf16x8*)(vrow1 + kv0 + 16 + hi * 8);  o1 = MFMA32(va, pf1a, o1);
  }

  // ---- merge the two kv-halves through LDS ----
  __shared__ float Sm[64][34];
  if (wid == 1) {
#pragma unroll
    for (int q4 = 0; q4 < 4; ++q4) {
      f32x4 a = { o0[q4*4+0], o0[q4*4+1], o0[q4*4+2], o0[q4*4+3] };
      f32x4 b = { o1[q4*4+0], o1[q4*4+1], o1[q4*4+2], o1[q4*4+3] };
      *(f32x4*)&Sm[lane][q4 * 4]      = a;
      *(f32x4*)&Sm[lane][16 + q4 * 4] = b;
    }
    Sm[lane][32] = M;
    Sm[lane][33] = L;
  }
  __syncthreads();
  if (wid == 0) {
    const float M1 = Sm[lane][32];
    const float L1 = Sm[lane][33];
    const float Ms = fmaxf(M, M1);
    const float r0 = exp2f((M  - Ms) * SC);
    const float r1 = exp2f((M1 - Ms) * SC);
    const float inv = 1.0f / (L * r0 + L1 * r1);

    const int b = bh >> 4, h = bh & 15;
    const int tq = qs + l31;
    __bf16* orow = Oc + (size_t)(b * 2048 + tq) * 1024 + h * 64;
#pragma unroll
    for (int q4 = 0; q4 < 4; ++q4) {
      bf16x4 v0, v1;
#pragma unroll
      for (int j = 0; j < 4; ++j) {
        const int r = q4 * 4 + j;
        v0[j] = (__bf16)((o0[r] * r0 + Sm[lane][r]      * r1) * inv);
        v1[j] = (__bf16)((o1[r] * r0 + Sm[lane][16 + r] * r1) * inv);
      }
      const int d0 = 8 * q4 + 4 * hi;
      *(bf16x4*)(orow + d0)      = v0;
      *(bf16x4*)(orow + 32 + d0) = v1;
    }
  }
}

extern "C" void kernel_launch(void* const* d_in, const int* in_sizes, int n_in,
                              void* d_out, int out_size, void* d_ws, size_t ws_size,
                              hipStream_t stream) {
  const float* x  = (const float*)d_in[0];
  const float* Wq = (const float*)d_in[1];
  const float* bq = (const float*)d_in[2];
  const float* Wk = (const float*)d_in[3];
  const float* bk = (const float*)d_in[4];
  const float* Wv = (const float*)d_in[5];
  const float* bv = (const float*)d_in[6];
  const float* Wp = (const float*)d_in[7];
  const float* bp = (const float*)d_in[8];

  __bf16* Qw  = (__bf16*)d_ws;                 // [32][2048][64]  8 MB
  __bf16* Kw  = Qw + (size_t)4194304;          // [32][2048][64]  8 MB
  __bf16* Vw  = Kw + (size_t)4194304;          // [32][64][2048]  8 MB (V^T)
  __bf16* xbA = Vw + (size_t)4194304;          // 8 MB: xb, then reused as Aw
  __bf16* Wb  = xbA + (size_t)4194304;         // [4][1024][1024] 8 MB bf16 weights

  conv_kernel<<<dim3(512, 5), 256, 0, stream>>>(x, Wq, Wk, Wv, Wp, xbA, Wb);
  gemm_qkv128<<<768, 256, 0, stream>>>(xbA, Wb, bq, bk, bv, Qw, Kw, Vw);
  attn_kernel<<<dim3(32, 64), 128, 0, stream>>>(Qw, Kw, Vw, xbA /*Aw*/);
  gemm_proj128<<<256, 256, 0, stream>>>(xbA /*Aw*/, Wb + (size_t)3 * 1048576,
                                        bp, (float*)d_out);
}

// Round 8
// 142.004 us; speedup vs baseline: 1.3020x; 1.0533x over previous
//
#include <hip/hip_runtime.h>
#include <hip/hip_bf16.h>

typedef __bf16 bf16x8 __attribute__((ext_vector_type(8)));
typedef __bf16 bf16x4 __attribute__((ext_vector_type(4)));
typedef __bf16 bf16x2 __attribute__((ext_vector_type(2)));
typedef float  f32x4  __attribute__((ext_vector_type(4)));
typedef float  f32x16v __attribute__((ext_vector_type(16)));

#define MFMA16(A,B,Cc) __builtin_amdgcn_mfma_f32_16x16x32_bf16(A,B,Cc,0,0,0)
#define MFMA32(A,B,Cc) __builtin_amdgcn_mfma_f32_32x32x16_bf16(A,B,Cc,0,0,0)

__device__ inline unsigned pack2(float a, float b) {
  union { bf16x2 v; unsigned u; } t;
  t.v[0] = (__bf16)a; t.v[1] = (__bf16)b;
  return t.u;
}
__device__ inline bf16x8 frag4(unsigned w0, unsigned w1, unsigned w2, unsigned w3) {
  union { unsigned u[4]; bf16x8 v; } t;
  t.u[0] = w0; t.u[1] = w1; t.u[2] = w2; t.u[3] = w3;
  return t.v;
}

// ---------------- f32 -> bf16 pre-convert (x + 4 weight matrices) ----------------
__global__ __launch_bounds__(256) void conv_kernel(
    const float* __restrict__ x,
    const float* __restrict__ Wq, const float* __restrict__ Wk,
    const float* __restrict__ Wv, const float* __restrict__ Wp,
    __bf16* __restrict__ xb, __bf16* __restrict__ Wb)
{
  const int z = blockIdx.y;
  const float* src;
  __bf16* dst;
  int n4;
  if (z == 0) { src = x;  dst = xb; n4 = 1048576; }
  else {
    src = (z == 1) ? Wq : (z == 2) ? Wk : (z == 3) ? Wv : Wp;
    dst = Wb + (size_t)(z - 1) * 1048576;
    n4  = 262144;
  }
  const f32x4* s4 = (const f32x4*)src;
  for (int i = blockIdx.x * 256 + threadIdx.x; i < n4; i += gridDim.x * 256) {
    const f32x4 v = s4[i];
    bf16x4 o;
#pragma unroll
    for (int j = 0; j < 4; ++j) o[j] = (__bf16)v[j];
    *(bf16x4*)(dst + (size_t)i * 4) = o;
  }
}

// ---------------- shared 128x128x(K=1024) bf16 MFMA core ----------------
__device__ inline void gemm_core(const __bf16* __restrict__ A,
                                 const __bf16* __restrict__ W,
                                 int m0, int n0,
                                 __bf16* As, __bf16* Bs,
                                 f32x4 (&acc)[4][4])
{
  const int tid = threadIdx.x, lane = tid & 63;
  const int wid = tid >> 6, wr = wid >> 1, wc = wid & 1;
  const int g = lane >> 4, cl = lane & 15;
  const int sr = tid >> 2, sk = (tid & 3) * 8;

  for (int k0 = 0; k0 < 1024; k0 += 32) {
    bf16x8 a0 = *(const bf16x8*)(A + (size_t)(m0 + sr)      * 1024 + k0 + sk);
    bf16x8 a1 = *(const bf16x8*)(A + (size_t)(m0 + sr + 64) * 1024 + k0 + sk);
    bf16x8 b0 = *(const bf16x8*)(W + (size_t)(n0 + sr)      * 1024 + k0 + sk);
    bf16x8 b1 = *(const bf16x8*)(W + (size_t)(n0 + sr + 64) * 1024 + k0 + sk);
    __syncthreads();
    *(bf16x8*)(As + sr * 32 + sk)        = a0;
    *(bf16x8*)(As + (sr + 64) * 32 + sk) = a1;
    *(bf16x8*)(Bs + sr * 32 + sk)        = b0;
    *(bf16x8*)(Bs + (sr + 64) * 32 + sk) = b1;
    __syncthreads();
    bf16x8 af[4], bfr[4];
#pragma unroll
    for (int m = 0; m < 4; ++m)
      af[m] = *(const bf16x8*)(As + (wr * 64 + m * 16 + cl) * 32 + g * 8);
#pragma unroll
    for (int n = 0; n < 4; ++n)
      bfr[n] = *(const bf16x8*)(Bs + (wc * 64 + n * 16 + cl) * 32 + g * 8);
#pragma unroll
    for (int m = 0; m < 4; ++m)
#pragma unroll
      for (int n = 0; n < 4; ++n)
        acc[m][n] = MFMA16(af[m], bfr[n], acc[m][n]);
  }
}

// ---------------- fused QKV GEMM (bf16 in, scattered bf16 out) ----------------
__global__ __launch_bounds__(256) void gemm_qkv128(
    const __bf16* __restrict__ xb, const __bf16* __restrict__ Wb,
    const float* __restrict__ bq, const float* __restrict__ bk,
    const float* __restrict__ bv,
    __bf16* __restrict__ Qw, __bf16* __restrict__ Kw, __bf16* __restrict__ Vw)
{
  __shared__ __align__(16) __bf16 As[128 * 32];
  __shared__ __align__(16) __bf16 Bs[128 * 32];

  const int orig = blockIdx.x;
  const int wg   = (orig & 7) * 96 + (orig >> 3);   // bijective: 768 = 8*96
  const int z    = wg >> 8;
  const int rem  = wg & 255;
  const int m0   = (rem >> 3) * 128;
  const int n0   = (rem & 7) * 128;

  const __bf16* W  = Wb + (size_t)z * 1048576;
  const float*  bi = (z == 0) ? bq : (z == 1) ? bk : bv;
  __bf16*       out = (z == 0) ? Qw : (z == 1) ? Kw : Vw;

  f32x4 acc[4][4] = {};
  gemm_core(xb, W, m0, n0, As, Bs, acc);

  const int lane = threadIdx.x & 63, wid = threadIdx.x >> 6;
  const int wr = wid >> 1, wc = wid & 1;
  const int g = lane >> 4, cl = lane & 15;

  float bvv[4];
#pragma unroll
  for (int n = 0; n < 4; ++n) bvv[n] = bi[n0 + wc * 64 + n * 16 + cl];

#pragma unroll
  for (int m = 0; m < 4; ++m)
#pragma unroll
    for (int n = 0; n < 4; ++n) {
      const int col = n0 + wc * 64 + n * 16 + cl;
      const int h = col >> 6, d = col & 63;
      if (z == 2) {                               // V^T scatter [BH][D][T]
        const int row0 = m0 + wr * 64 + m * 16 + g * 4;
        const int b2 = row0 >> 11, t0 = row0 & 2047;
        bf16x4 v4;
#pragma unroll
        for (int j = 0; j < 4; ++j) v4[j] = (__bf16)(acc[m][n][j] + bvv[n]);
        *(bf16x4*)(out + (size_t)(b2 * 16 + h) * 131072 + (size_t)d * 2048 + t0) = v4;
      } else {                                    // Q/K scatter [BH][T][D]
#pragma unroll
        for (int j = 0; j < 4; ++j) {
          const int row = m0 + wr * 64 + m * 16 + g * 4 + j;
          const int b2 = row >> 11, t = row & 2047;
          out[(size_t)(b2 * 16 + h) * 131072 + (size_t)t * 64 + d] =
              (__bf16)(acc[m][n][j] + bvv[n]);
        }
      }
    }
}

// ---------------- projection GEMM (bf16 in, f32 out) ----------------
__global__ __launch_bounds__(256) void gemm_proj128(
    const __bf16* __restrict__ A, const __bf16* __restrict__ W,
    const float* __restrict__ bi, float* __restrict__ outp)
{
  __shared__ __align__(16) __bf16 As[128 * 32];
  __shared__ __align__(16) __bf16 Bs[128 * 32];

  const int orig = blockIdx.x;
  const int wg   = (orig & 7) * 32 + (orig >> 3);   // bijective: 256 = 8*32
  const int m0   = (wg >> 3) * 128;
  const int n0   = (wg & 7) * 128;

  f32x4 acc[4][4] = {};
  gemm_core(A, W, m0, n0, As, Bs, acc);

  const int lane = threadIdx.x & 63, wid = threadIdx.x >> 6;
  const int wr = wid >> 1, wc = wid & 1;
  const int g = lane >> 4, cl = lane & 15;

  float bvv[4];
#pragma unroll
  for (int n = 0; n < 4; ++n) bvv[n] = bi[n0 + wc * 64 + n * 16 + cl];
#pragma unroll
  for (int m = 0; m < 4; ++m)
#pragma unroll
    for (int n = 0; n < 4; ++n) {
      const int col = n0 + wc * 64 + n * 16 + cl;
#pragma unroll
      for (int j = 0; j < 4; ++j) {
        const int row = m0 + wr * 64 + m * 16 + g * 4 + j;
        outp[(size_t)row * 1024 + col] = acc[m][n][j] + bvv[n];
      }
    }
}

// ---------------- causal flash attention: strip-paired, uniform work ----------------
// Pair strip p with strip 63-p: every block = 65 kv-tiles exactly. 1024 blocks
// x 4 waves, wave w takes tiles t==w (mod 4) of each strip. Partials (O bf16,
// M/L f32) stashed in LDS between phases; waves 0/1 do the 4-way softmax merge.
__device__ inline void attn_tile(
    const __bf16* __restrict__ Kb, const __bf16* __restrict__ vrow0,
    const __bf16* __restrict__ vrow1, const bf16x8 (&qf)[4],
    int kv0, bool diag, int l31, int hi,
    float& M, float& MS, float& L, f32x16v& o0, f32x16v& o1)
{
  const float SC = 0.18033688f;                 // 0.125 * log2(e)
  const float DT = 16.6f;                       // defer-max: P bounded by 2^3
  f32x16v s = {};
#pragma unroll
  for (int c = 0; c < 4; ++c) {
    bf16x8 kf = *(const bf16x8*)(Kb + (kv0 + l31) * 64 + c * 16 + hi * 8);
    s = MFMA32(kf, qf[c], s);
  }
  float sv[16];
#pragma unroll
  for (int r = 0; r < 16; ++r) sv[r] = s[r];
  if (diag) {
#pragma unroll
    for (int r = 0; r < 16; ++r) {
      const int kl = (r & 3) + 8 * (r >> 2) + 4 * hi;
      if (kl > l31) sv[r] = -1e30f;
    }
  }
  float mt = sv[0];
#pragma unroll
  for (int r = 1; r < 16; ++r) mt = fmaxf(mt, sv[r]);
  mt = fmaxf(mt, __shfl_xor(mt, 32, 64));
  if (!__all(mt <= M + DT)) {
    const float Mn = fmaxf(M, mt);
    const float rs = exp2f((M - Mn) * SC);
    o0 *= rs; o1 *= rs; L *= rs; M = Mn; MS = M * SC;
  }
  float p[16];
  float lt = 0.f;
#pragma unroll
  for (int r = 0; r < 16; ++r) {
    p[r] = exp2f(__builtin_fmaf(sv[r], SC, -MS));
    lt += p[r];
  }
  lt += __shfl_xor(lt, 32, 64);
  L += lt;

  const unsigned c0 = pack2(p[0],  p[1]),  c1 = pack2(p[2],  p[3]);
  const unsigned c2 = pack2(p[4],  p[5]),  c3 = pack2(p[6],  p[7]);
  const unsigned c4 = pack2(p[8],  p[9]),  c5 = pack2(p[10], p[11]);
  const unsigned c6 = pack2(p[12], p[13]), c7 = pack2(p[14], p[15]);
  const unsigned x0 = __shfl_xor(c0, 32, 64), x1 = __shfl_xor(c1, 32, 64);
  const unsigned x2 = __shfl_xor(c2, 32, 64), x3 = __shfl_xor(c3, 32, 64);
  const unsigned x4 = __shfl_xor(c4, 32, 64), x5 = __shfl_xor(c5, 32, 64);
  const unsigned x6 = __shfl_xor(c6, 32, 64), x7 = __shfl_xor(c7, 32, 64);
  const bf16x8 pf0 = frag4(hi ? x2 : c0, hi ? x3 : c1, hi ? c2 : x0, hi ? c3 : x1);
  const bf16x8 pf1 = frag4(hi ? x6 : c4, hi ? x7 : c5, hi ? c6 : x4, hi ? c7 : x5);

  bf16x8 va;
  va = *(const bf16x8*)(vrow0 + kv0 + hi * 8);       o0 = MFMA32(va, pf0, o0);
  va = *(const bf16x8*)(vrow1 + kv0 + hi * 8);       o1 = MFMA32(va, pf0, o1);
  va = *(const bf16x8*)(vrow0 + kv0 + 16 + hi * 8);  o0 = MFMA32(va, pf1, o0);
  va = *(const bf16x8*)(vrow1 + kv0 + 16 + hi * 8);  o1 = MFMA32(va, pf1, o1);
}

__global__ __launch_bounds__(256, 4) void attn_kernel(
    const __bf16* __restrict__ Q, const __bf16* __restrict__ K,
    const __bf16* __restrict__ Vt, __bf16* __restrict__ Oc)
{
  const int bh  = blockIdx.x;
  const int p   = blockIdx.y;                   // pair: strips p and 63-p
  const int w   = threadIdx.x >> 6;
  const int lane = threadIdx.x & 63;
  const int l31 = lane & 31, hi = lane >> 5;
  const float SC = 0.18033688f;

  const __bf16* Qb = Q  + (size_t)bh * 131072;
  const __bf16* Kb = K  + (size_t)bh * 131072;
  const __bf16* Vb = Vt + (size_t)bh * 131072;
  const __bf16* vrow0 = Vb + (size_t)l31 * 2048;
  const __bf16* vrow1 = Vb + (size_t)(32 + l31) * 2048;

  __shared__ __bf16 SO[8][64][32];              // partial O (bf16)
  __shared__ float  SML[8][64][2];              // partial M, L

  const int qsS[2] = { p * 32, (63 - p) * 32 };
  const int nS[2]  = { p + 1, 64 - p };

#pragma unroll
  for (int ph = 0; ph < 2; ++ph) {
    const int qs = qsS[ph], nT = nS[ph];
    bf16x8 qf[4];
#pragma unroll
    for (int c = 0; c < 4; ++c)
      qf[c] = *(const bf16x8*)(Qb + (qs + l31) * 64 + c * 16 + hi * 8);

    f32x16v o0 = {}, o1 = {};
    float M = -1e30f, L = 0.f;
    float MS = M * SC;

    for (int t = w; t < nT; t += 4)
      attn_tile(Kb, vrow0, vrow1, qf, t * 32, t == nT - 1, l31, hi,
                M, MS, L, o0, o1);

    const int slot = ph * 4 + w;
#pragma unroll
    for (int q4 = 0; q4 < 4; ++q4) {
      bf16x4 a, b;
#pragma unroll
      for (int j = 0; j < 4; ++j) {
        a[j] = (__bf16)o0[q4 * 4 + j];
        b[j] = (__bf16)o1[q4 * 4 + j];
      }
      *(bf16x4*)&SO[slot][lane][q4 * 4]      = a;
      *(bf16x4*)&SO[slot][lane][16 + q4 * 4] = b;
    }
    SML[slot][lane][0] = M;
    SML[slot][lane][1] = L;
  }

  __syncthreads();
  if (w < 2) {                                  // wave 0 -> strip A, wave 1 -> strip B
    const int base = w * 4;
    const int qs = qsS[w];
    float Mw[4], Lw[4];
#pragma unroll
    for (int s = 0; s < 4; ++s) {
      Mw[s] = SML[base + s][lane][0];
      Lw[s] = SML[base + s][lane][1];
    }
    const float Ms = fmaxf(fmaxf(Mw[0], Mw[1]), fmaxf(Mw[2], Mw[3]));
    float r[4], Lt = 0.f;
#pragma unroll
    for (int s = 0; s < 4; ++s) {
      r[s] = exp2f((Mw[s] - Ms) * SC);
      Lt += Lw[s] * r[s];
    }
    const float inv = 1.0f / Lt;

    const int b = bh >> 4, h = bh & 15;
    const int tq = qs + l31;
    __bf16* orow = Oc + (size_t)(b * 2048 + tq) * 1024 + h * 64;
#pragma unroll
    for (int q4 = 0; q4 < 4; ++q4) {
      bf16x4 v0, v1;
#pragma unroll
      for (int j = 0; j < 4; ++j) {
        const int ri = q4 * 4 + j;
        float a = 0.f, bb = 0.f;
#pragma unroll
        for (int s = 0; s < 4; ++s) {
          a  += (float)SO[base + s][lane][ri]      * r[s];
          bb += (float)SO[base + s][lane][16 + ri] * r[s];
        }
        v0[j] = (__bf16)(a * inv);
        v1[j] = (__bf16)(bb * inv);
      }
      const int d0 = 8 * q4 + 4 * hi;
      *(bf16x4*)(orow + d0)      = v0;
      *(bf16x4*)(orow + 32 + d0) = v1;
    }
  }
}

extern "C" void kernel_launch(void* const* d_in, const int* in_sizes, int n_in,
                              void* d_out, int out_size, void* d_ws, size_t ws_size,
                              hipStream_t stream) {
  const float* x  = (const float*)d_in[0];
  const float* Wq = (const float*)d_in[1];
  const float* bq = (const float*)d_in[2];
  const float* Wk = (const float*)d_in[3];
  const float* bk = (const float*)d_in[4];
  const float* Wv = (const float*)d_in[5];
  const float* bv = (const float*)d_in[6];
  const float* Wp = (const float*)d_in[7];
  const float* bp = (const float*)d_in[8];

  __bf16* Qw  = (__bf16*)d_ws;                 // [32][2048][64]  8 MB
  __bf16* Kw  = Qw + (size_t)4194304;          // [32][2048][64]  8 MB
  __bf16* Vw  = Kw + (size_t)4194304;          // [32][64][2048]  8 MB (V^T)
  __bf16* xbA = Vw + (size_t)4194304;          // 8 MB: xb, then reused as Aw
  __bf16* Wb  = xbA + (size_t)4194304;         // [4][1024][1024] 8 MB bf16 weights

  conv_kernel<<<dim3(512, 5), 256, 0, stream>>>(x, Wq, Wk, Wv, Wp, xbA, Wb);
  gemm_qkv128<<<768, 256, 0, stream>>>(xbA, Wb, bq, bk, bv, Qw, Kw, Vw);
  attn_kernel<<<dim3(32, 32), 256, 0, stream>>>(Qw, Kw, Vw, xbA /*Aw*/);
  gemm_proj128<<<256, 256, 0, stream>>>(xbA /*Aw*/, Wb + (size_t)3 * 1048576,
                                        bp, (float*)d_out);
}